// Round 1
// baseline (365.789 us; speedup 1.0000x reference)
//
#include <hip/hip_runtime.h>
#include <math.h>

#define BB 64
#define NN 4096
#define DD 1024
#define CC 1000
#define NCHUNK 32               // n-chunks per batch in k3
#define CHUNK (NN / NCHUNK)     // 128 rows per chunk
#define C4 (CC / 4)             // 250 float4 per label row

// K1: scores[b][n] = -||q_b - s_{b,n}||  (one wave per row, 4 rows/block)
__global__ void k1_scores(const float* __restrict__ q,
                          const float* __restrict__ s,
                          float* __restrict__ scores) {
    const int wave = threadIdx.x >> 6;
    const int lane = threadIdx.x & 63;
    const long long row = (long long)blockIdx.x * 4 + wave;   // [0, BB*NN)
    const int b = (int)(row >> 12);                            // row / 4096
    const float4* qv = (const float4*)(q + (long long)b * DD);
    const float4* sv = (const float4*)(s + row * DD);
    float acc = 0.f;
#pragma unroll
    for (int i = 0; i < 4; ++i) {
        float4 a  = qv[lane + 64 * i];
        float4 bb = sv[lane + 64 * i];
        float dx = a.x - bb.x, dy = a.y - bb.y;
        float dz = a.z - bb.z, dw = a.w - bb.w;
        acc += dx * dx + dy * dy + dz * dz + dw * dw;
    }
#pragma unroll
    for (int off = 32; off > 0; off >>= 1)
        acc += __shfl_down(acc, off, 64);
    if (lane == 0) scores[row] = -sqrtf(acc);
}

// K2: in-place softmax over n per batch. 64 blocks x 256 threads, 16 vals/thread.
__global__ void k2_softmax(float* __restrict__ sc) {
    const int b = blockIdx.x;
    const int t = threadIdx.x;
    const int wave = t >> 6, lane = t & 63;
    float* p = sc + (long long)b * NN;
    float v[16];
    float m = -1e30f;
#pragma unroll
    for (int i = 0; i < 16; ++i) {
        v[i] = p[t + 256 * i];
        m = fmaxf(m, v[i]);
    }
#pragma unroll
    for (int off = 32; off > 0; off >>= 1)
        m = fmaxf(m, __shfl_down(m, off, 64));
    __shared__ float wmax[4], wsum[4];
    if (lane == 0) wmax[wave] = m;
    __syncthreads();
    m = fmaxf(fmaxf(wmax[0], wmax[1]), fmaxf(wmax[2], wmax[3]));
    float ssum = 0.f;
#pragma unroll
    for (int i = 0; i < 16; ++i) {
        v[i] = __expf(v[i] - m);
        ssum += v[i];
    }
#pragma unroll
    for (int off = 32; off > 0; off >>= 1)
        ssum += __shfl_down(ssum, off, 64);
    if (lane == 0) wsum[wave] = ssum;
    __syncthreads();
    const float inv = 1.f / (wsum[0] + wsum[1] + wsum[2] + wsum[3]);
#pragma unroll
    for (int i = 0; i < 16; ++i)
        p[t + 256 * i] = v[i] * inv;
}

// K3: partial out[b][chunk][c] = sum_{n in chunk} probs[b][n] * labels[b][n][c]
__global__ void k3_partial(const float* __restrict__ probs,
                           const float* __restrict__ labels,
                           float* __restrict__ part) {
    const int b  = blockIdx.x >> 5;        // / NCHUNK
    const int ch = blockIdx.x & (NCHUNK - 1);
    const int t  = threadIdx.x;            // 256 threads; t<250 do float4 work
    const int n0 = ch * CHUNK;
    __shared__ float pl[CHUNK];
    if (t < CHUNK) pl[t] = probs[(long long)b * NN + n0 + t];
    __syncthreads();
    if (t < C4) {
        const float4* lb = (const float4*)(labels + ((long long)b * NN + n0) * CC);
        float4 acc = {0.f, 0.f, 0.f, 0.f};
#pragma unroll 4
        for (int i = 0; i < CHUNK; ++i) {
            const float pp = pl[i];
            float4 l = lb[(long long)i * C4 + t];
            acc.x += pp * l.x; acc.y += pp * l.y;
            acc.z += pp * l.z; acc.w += pp * l.w;
        }
        float4* o = (float4*)(part + ((long long)b * NCHUNK + ch) * CC);
        o[t] = acc;
    }
}

// K4: out[b][c] = sum_chunk part[b][chunk][c]
__global__ void k4_reduce(const float* __restrict__ part, float* __restrict__ out) {
    const int b = blockIdx.x;
    const int t = threadIdx.x;
    if (t >= C4) return;
    const float4* p = (const float4*)(part + (long long)b * NCHUNK * CC);
    float4 acc = {0.f, 0.f, 0.f, 0.f};
#pragma unroll
    for (int i = 0; i < NCHUNK; ++i) {
        float4 v = p[(long long)i * C4 + t];
        acc.x += v.x; acc.y += v.y; acc.z += v.z; acc.w += v.w;
    }
    ((float4*)(out + (long long)b * CC))[t] = acc;
}

extern "C" void kernel_launch(void* const* d_in, const int* in_sizes, int n_in,
                              void* d_out, int out_size, void* d_ws, size_t ws_size,
                              hipStream_t stream) {
    const float* q   = (const float*)d_in[0];   // (64, 1024)
    const float* s   = (const float*)d_in[1];   // (64, 4096, 1024)
    const float* lab = (const float*)d_in[2];   // (64, 4096, 1000)
    float* out = (float*)d_out;                 // (64, 1000)

    float* scores = (float*)d_ws;               // BB*NN floats = 1 MB
    float* part   = scores + (long long)BB * NN; // BB*NCHUNK*CC floats = 8.2 MB

    k1_scores<<<BB * NN / 4, 256, 0, stream>>>(q, s, scores);
    k2_softmax<<<BB, 256, 0, stream>>>(scores);
    k3_partial<<<BB * NCHUNK, 256, 0, stream>>>(scores, lab, part);
    k4_reduce<<<BB, 256, 0, stream>>>(part, out);
}

// Round 2
// 323.893 us; speedup vs baseline: 1.1294x; 1.1294x over previous
//
#include <hip/hip_runtime.h>
#include <math.h>

#define BB 64
#define NN 4096
#define DD 1024
#define CC 1000
#define NCHUNK 32               // n-chunks per batch in k3
#define CHUNK (NN / NCHUNK)     // 128 rows per chunk
#define C4 (CC / 4)             // 250 float4 per label row

typedef float f4 __attribute__((ext_vector_type(4)));

// K1: scores[b][n] = -||q_b - s_{b,n}||  (one wave per row, 4 rows/block)
// q row staged in LDS once per block (all 4 waves share the batch).
__global__ void k1_scores(const float* __restrict__ q,
                          const float* __restrict__ s,
                          float* __restrict__ scores) {
    const int wave = threadIdx.x >> 6;
    const int lane = threadIdx.x & 63;
    const long long row = (long long)blockIdx.x * 4 + wave;   // [0, BB*NN)
    const int b = (int)(row >> 12);                            // row / 4096

    __shared__ f4 qs[DD / 4];                                  // 4 KB
    {
        const f4* qv = (const f4*)(q + (long long)b * DD);
        // 256 threads load 256 float4 = whole q row
        qs[threadIdx.x] = qv[threadIdx.x];
    }
    __syncthreads();

    const f4* sv = (const f4*)(s + row * DD);
    float acc = 0.f;
#pragma unroll
    for (int i = 0; i < 4; ++i) {
        f4 a  = qs[lane + 64 * i];
        f4 bb = __builtin_nontemporal_load(sv + lane + 64 * i);
        float dx = a.x - bb.x, dy = a.y - bb.y;
        float dz = a.z - bb.z, dw = a.w - bb.w;
        acc += dx * dx + dy * dy + dz * dz + dw * dw;
    }
#pragma unroll
    for (int off = 32; off > 0; off >>= 1)
        acc += __shfl_down(acc, off, 64);
    if (lane == 0) scores[row] = -sqrtf(acc);
}

// K2: in-place softmax over n per batch. 64 blocks x 256 threads, 16 vals/thread.
__global__ void k2_softmax(float* __restrict__ sc) {
    const int b = blockIdx.x;
    const int t = threadIdx.x;
    const int wave = t >> 6, lane = t & 63;
    float* p = sc + (long long)b * NN;
    float v[16];
    float m = -1e30f;
#pragma unroll
    for (int i = 0; i < 16; ++i) {
        v[i] = p[t + 256 * i];
        m = fmaxf(m, v[i]);
    }
#pragma unroll
    for (int off = 32; off > 0; off >>= 1)
        m = fmaxf(m, __shfl_down(m, off, 64));
    __shared__ float wmax[4], wsum[4];
    if (lane == 0) wmax[wave] = m;
    __syncthreads();
    m = fmaxf(fmaxf(wmax[0], wmax[1]), fmaxf(wmax[2], wmax[3]));
    float ssum = 0.f;
#pragma unroll
    for (int i = 0; i < 16; ++i) {
        v[i] = __expf(v[i] - m);
        ssum += v[i];
    }
#pragma unroll
    for (int off = 32; off > 0; off >>= 1)
        ssum += __shfl_down(ssum, off, 64);
    if (lane == 0) wsum[wave] = ssum;
    __syncthreads();
    const float inv = 1.f / (wsum[0] + wsum[1] + wsum[2] + wsum[3]);
#pragma unroll
    for (int i = 0; i < 16; ++i)
        p[t + 256 * i] = v[i] * inv;
}

// K3: partial out[b][chunk][c] = sum_{n in chunk} probs[b][n] * labels[b][n][c]
__global__ void k3_partial(const float* __restrict__ probs,
                           const float* __restrict__ labels,
                           float* __restrict__ part) {
    const int b  = blockIdx.x >> 5;        // / NCHUNK
    const int ch = blockIdx.x & (NCHUNK - 1);
    const int t  = threadIdx.x;            // 256 threads; t<250 do float4 work
    const int n0 = ch * CHUNK;
    __shared__ float pl[CHUNK];
    if (t < CHUNK) pl[t] = probs[(long long)b * NN + n0 + t];
    __syncthreads();
    if (t < C4) {
        const f4* lb = (const f4*)(labels + ((long long)b * NN + n0) * CC);
        f4 acc = {0.f, 0.f, 0.f, 0.f};
#pragma unroll 8
        for (int i = 0; i < CHUNK; ++i) {
            const float pp = pl[i];
            f4 l = __builtin_nontemporal_load(lb + (long long)i * C4 + t);
            acc.x += pp * l.x; acc.y += pp * l.y;
            acc.z += pp * l.z; acc.w += pp * l.w;
        }
        f4* o = (f4*)(part + ((long long)b * NCHUNK + ch) * CC);
        o[t] = acc;
    }
}

// K4: out[b][c] = sum_chunk part[b][chunk][c]
__global__ void k4_reduce(const float* __restrict__ part, float* __restrict__ out) {
    const int b = blockIdx.x;
    const int t = threadIdx.x;
    if (t >= C4) return;
    const f4* p = (const f4*)(part + (long long)b * NCHUNK * CC);
    f4 acc = {0.f, 0.f, 0.f, 0.f};
#pragma unroll
    for (int i = 0; i < NCHUNK; ++i) {
        f4 v = __builtin_nontemporal_load(p + (long long)i * C4 + t);
        acc.x += v.x; acc.y += v.y; acc.z += v.z; acc.w += v.w;
    }
    ((f4*)(out + (long long)b * CC))[t] = acc;
}

extern "C" void kernel_launch(void* const* d_in, const int* in_sizes, int n_in,
                              void* d_out, int out_size, void* d_ws, size_t ws_size,
                              hipStream_t stream) {
    const float* q   = (const float*)d_in[0];   // (64, 1024)
    const float* s   = (const float*)d_in[1];   // (64, 4096, 1024)
    const float* lab = (const float*)d_in[2];   // (64, 4096, 1000)
    float* out = (float*)d_out;                 // (64, 1000)

    float* scores = (float*)d_ws;               // BB*NN floats = 1 MB
    float* part   = scores + (long long)BB * NN; // BB*NCHUNK*CC floats = 8.2 MB

    k1_scores<<<BB * NN / 4, 256, 0, stream>>>(q, s, scores);
    k2_softmax<<<BB, 256, 0, stream>>>(scores);
    k3_partial<<<BB * NCHUNK, 256, 0, stream>>>(scores, lab, part);
    k4_reduce<<<BB, 256, 0, stream>>>(part, out);
}